// Round 1
// baseline (677.435 us; speedup 1.0000x reference)
//
#include <hip/hip_runtime.h>
#include <cfloat>
#include <math.h>

// Problem constants (B=4, T=32, N=96, K=30, NUM_HIDDEN=128, NUM_IN=256, H=4, d=32)
constexpr int SITES = 12288;   // B*T*N
constexpr int KNB   = 30;      // neighbors
constexpr int CIN   = 256;     // NUM_IN
constexpr int HID   = 128;     // NUM_HIDDEN
#define RSQRT_D 0.17677669529663689f   // 1/sqrt(32)

// ---------------------------------------------------------------------------
// Weight precompute:
//   Mbuf[i*1024 + h*256 + c] = sum_d Wq[i][h*32+d] * Wk[c][h*32+d]    (128x1024)
//   W3[(h*256+c)*128 + j]    = sum_d Wv[c][h*32+d] * Wo[h*32+d][j]    (1024x128)
// ---------------------------------------------------------------------------
__global__ __launch_bounds__(256) void precompute_kernel(
    const float* __restrict__ Wq, const float* __restrict__ Wk,
    const float* __restrict__ Wv, const float* __restrict__ Wo,
    float* __restrict__ Mbuf, float* __restrict__ W3) {
    int gid = blockIdx.x * 256 + threadIdx.x;
    if (gid < 131072) {
        int i = gid >> 10;
        int rest = gid & 1023;
        int h = rest >> 8;
        int c = rest & 255;
        float s = 0.f;
        #pragma unroll
        for (int d = 0; d < 32; ++d)
            s += Wq[i * 128 + h * 32 + d] * Wk[c * 128 + h * 32 + d];
        Mbuf[gid] = s;
    } else {
        int o = gid - 131072;
        int p = o >> 7;          // h*256+c
        int j = o & 127;
        int h = p >> 8;
        int c = p & 255;
        float s = 0.f;
        #pragma unroll
        for (int d = 0; d < 32; ++d)
            s += Wv[c * 128 + h * 32 + d] * Wo[(h * 32 + d) * 128 + j];
        W3[o] = s;
    }
}

// ---------------------------------------------------------------------------
// Generic fp32 tiled GEMM: C(MxN) = A(MxK) @ B(KxN), all row-major.
// 256 threads, (BM/TM)*(BN/TN) == 256, dims divide tile sizes evenly.
// ---------------------------------------------------------------------------
template <int BM, int BN, int BK, int TM, int TN>
__global__ __launch_bounds__(256) void gemm_f32(
    const float* __restrict__ A, const float* __restrict__ B,
    float* __restrict__ C, int M, int N, int K) {
    __shared__ float As[BK][BM];
    __shared__ float Bs[BK][BN];
    const int tid = threadIdx.x;
    const int tx = tid % (BN / TN);
    const int ty = tid / (BN / TN);
    const int bm0 = blockIdx.x * BM;
    const int bn0 = blockIdx.y * BN;

    float acc[TM][TN];
    #pragma unroll
    for (int i = 0; i < TM; ++i)
        #pragma unroll
        for (int j = 0; j < TN; ++j) acc[i][j] = 0.f;

    constexpr int A4 = BM * BK / 4;
    constexpr int B4 = BK * BN / 4;

    for (int kk = 0; kk < K; kk += BK) {
        #pragma unroll
        for (int i = tid; i < A4; i += 256) {
            int row = i / (BK / 4);
            int c4 = i % (BK / 4);
            float4 v = *(const float4*)(A + (size_t)(bm0 + row) * K + kk + c4 * 4);
            As[c4 * 4 + 0][row] = v.x;
            As[c4 * 4 + 1][row] = v.y;
            As[c4 * 4 + 2][row] = v.z;
            As[c4 * 4 + 3][row] = v.w;
        }
        #pragma unroll
        for (int i = tid; i < B4; i += 256) {
            int row = i / (BN / 4);
            int c4 = i % (BN / 4);
            float4 v = *(const float4*)(B + (size_t)(kk + row) * N + bn0 + c4 * 4);
            *(float4*)&Bs[row][c4 * 4] = v;
        }
        __syncthreads();
        #pragma unroll
        for (int k = 0; k < BK; ++k) {
            float a[TM], b[TN];
            #pragma unroll
            for (int i = 0; i < TM; ++i) a[i] = As[k][ty * TM + i];
            #pragma unroll
            for (int j = 0; j < TN; ++j) b[j] = Bs[k][tx * TN + j];
            #pragma unroll
            for (int i = 0; i < TM; ++i)
                #pragma unroll
                for (int j = 0; j < TN; ++j) acc[i][j] += a[i] * b[j];
        }
        __syncthreads();
    }
    #pragma unroll
    for (int i = 0; i < TM; ++i)
        #pragma unroll
        for (int j = 0; j < TN; ++j)
            C[(size_t)(bm0 + ty * TM + i) * N + bn0 + tx * TN + j] = acc[i][j];
}

// ---------------------------------------------------------------------------
// Fused neighbor attention: one workgroup (256 thr = 4 waves) per site.
//  - q~ row (1024 fp32) loaded into registers (16/lane)
//  - stream EV slice (30x256) once: float4 loads, logits via in-flight dot +
//    64-lane shuffle reduce; slice staged to LDS
//  - masked softmax (one wave per head)
//  - evbar[h][c] = sum_k attend[h][k] * EV[k][c]  from LDS
// ---------------------------------------------------------------------------
__global__ __launch_bounds__(256) void attn_kernel(
    const float* __restrict__ hEV, const int* __restrict__ mask,
    const float* __restrict__ qt, float* __restrict__ evbar) {
    __shared__ float evS[KNB * CIN];      // 30*256 fp32 = 30 KB
    __shared__ float logitsL[4 * 32];
    __shared__ float attendL[4 * 32];
    __shared__ int   maskL[32];

    const int s = blockIdx.x;
    const int tid = threadIdx.x;
    const int lane = tid & 63;

    // q~ fragments: lane holds q~[h*256 + lane*4 .. +3] for h=0..3
    const float4* q4 = (const float4*)(qt + (size_t)s * 1024);
    float4 q0 = q4[lane];
    float4 q1 = q4[64 + lane];
    float4 q2 = q4[128 + lane];
    float4 q3 = q4[192 + lane];

    if (tid < KNB) maskL[tid] = mask[(size_t)s * KNB + tid];

    // Stream EV slice: 1920 float4 total; wave w handles row k = j*4+w per iter
    const float4* ev4 = (const float4*)(hEV + (size_t)s * (KNB * CIN));
    #pragma unroll
    for (int j = 0; j < 8; ++j) {
        int idx = j * 256 + tid;             // = k*64 + lane (row-aligned)
        if (idx < KNB * 64) {
            float4 v = ev4[idx];
            *(float4*)&evS[idx * 4] = v;
            float l0 = v.x * q0.x + v.y * q0.y + v.z * q0.z + v.w * q0.w;
            float l1 = v.x * q1.x + v.y * q1.y + v.z * q1.z + v.w * q1.w;
            float l2 = v.x * q2.x + v.y * q2.y + v.z * q2.z + v.w * q2.w;
            float l3 = v.x * q3.x + v.y * q3.y + v.z * q3.z + v.w * q3.w;
            #pragma unroll
            for (int m = 1; m < 64; m <<= 1) {
                l0 += __shfl_xor(l0, m, 64);
                l1 += __shfl_xor(l1, m, 64);
                l2 += __shfl_xor(l2, m, 64);
                l3 += __shfl_xor(l3, m, 64);
            }
            if (lane == 0) {
                int k = idx >> 6;
                logitsL[0 * 32 + k] = l0 * RSQRT_D;
                logitsL[1 * 32 + k] = l1 * RSQRT_D;
                logitsL[2 * 32 + k] = l2 * RSQRT_D;
                logitsL[3 * 32 + k] = l3 * RSQRT_D;
            }
        }
    }
    __syncthreads();

    // Masked softmax: wave w handles head h=w, lane = k
    {
        int h = tid >> 6;
        int mk = (lane < KNB) ? maskL[lane] : 0;
        float lg = -FLT_MAX;
        if (mk > 0) lg = logitsL[h * 32 + lane];
        float mx = lg;
        #pragma unroll
        for (int m = 1; m < 64; m <<= 1) mx = fmaxf(mx, __shfl_xor(mx, m, 64));
        float e = 0.f;
        if (mk > 0) e = __expf(lg - mx);
        float sm = e;
        #pragma unroll
        for (int m = 1; m < 64; m <<= 1) sm += __shfl_xor(sm, m, 64);
        float at = (sm > 0.f) ? e / sm : 0.f;
        if (lane < KNB) attendL[h * 32 + lane] = at;
    }
    __syncthreads();

    // evbar: thread t owns column c = t
    float a0 = 0.f, a1 = 0.f, a2 = 0.f, a3 = 0.f;
    #pragma unroll 6
    for (int k = 0; k < KNB; ++k) {
        float evv = evS[k * CIN + tid];
        a0 += attendL[0 * 32 + k] * evv;
        a1 += attendL[1 * 32 + k] * evv;
        a2 += attendL[2 * 32 + k] * evv;
        a3 += attendL[3 * 32 + k] * evv;
    }
    size_t ob = (size_t)s * 1024 + tid;
    evbar[ob + 0]   = a0;
    evbar[ob + 256] = a1;
    evbar[ob + 512] = a2;
    evbar[ob + 768] = a3;
}

// ---------------------------------------------------------------------------
extern "C" void kernel_launch(void* const* d_in, const int* in_sizes, int n_in,
                              void* d_out, int out_size, void* d_ws, size_t ws_size,
                              hipStream_t stream) {
    const float* hV   = (const float*)d_in[0];
    const float* hEV  = (const float*)d_in[1];
    const int*   mask = (const int*)d_in[2];
    const float* Wq   = (const float*)d_in[3];
    const float* Wk   = (const float*)d_in[4];
    const float* Wv   = (const float*)d_in[5];
    const float* Wo   = (const float*)d_in[6];
    float* out = (float*)d_out;

    float* ws    = (float*)d_ws;
    float* Mbuf  = ws;                               // 128*1024
    float* W3    = ws + 131072;                      // 1024*128
    float* qt    = ws + 262144;                      // 12288*1024
    float* evbar = qt + (size_t)SITES * 1024;        // 12288*1024
    size_t need = ((size_t)262144 + 2 * (size_t)SITES * 1024) * sizeof(float);
    if (ws_size < need) return;

    // 1) weight-only precompute
    precompute_kernel<<<dim3(1024), dim3(256), 0, stream>>>(Wq, Wk, Wv, Wo, Mbuf, W3);

    // 2) q~ = h_V (12288x128) @ Mbuf (128x1024)
    gemm_f32<64, 64, 32, 4, 4><<<dim3(SITES / 64, 1024 / 64), dim3(256), 0, stream>>>(
        hV, Mbuf, qt, SITES, 1024, 128);

    // 3) fused masked neighbor attention -> evbar (12288x1024)
    attn_kernel<<<dim3(SITES), dim3(256), 0, stream>>>(hEV, mask, qt, evbar);

    // 4) out = evbar (12288x1024) @ W3 (1024x128)
    gemm_f32<64, 32, 32, 4, 2><<<dim3(SITES / 64, 128 / 32), dim3(256), 0, stream>>>(
        evbar, W3, out, SITES, 128, 1024);
}

// Round 2
// 517.153 us; speedup vs baseline: 1.3099x; 1.3099x over previous
//
#include <hip/hip_runtime.h>
#include <hip/hip_bf16.h>
#include <cfloat>
#include <math.h>

// Problem: B=4,T=32,N=96,K=30, NUM_HIDDEN=128, NUM_IN=256, H=4, d=32
constexpr int SITES = 12288;
constexpr int KNB   = 30;
constexpr int CIN   = 256;
#define RSQRT_D 0.17677669529663689f

typedef short bf16x8 __attribute__((ext_vector_type(8)));   // 8 bf16 in 4 VGPRs
typedef float f32x4  __attribute__((ext_vector_type(4)));

__device__ inline unsigned short f2bs(float x) {
    __hip_bfloat16 b = __float2bfloat16(x);            // RTN-even
    return *(unsigned short*)&b;
}
__device__ inline float bs2f(unsigned short u) {
    unsigned int v = (unsigned int)u << 16;
    float f;
    __builtin_memcpy(&f, &v, 4);
    return f;
}
__device__ inline unsigned int pack2(float a, float b) {
    return (unsigned int)f2bs(a) | ((unsigned int)f2bs(b) << 16);
}

// ---------------------------------------------------------------------------
// Weight precompute (bf16, transposed for B^T GEMM):
//   Mt[(h*256+c)*128 + i] = sum_d Wq[i][h*32+d] * Wk[c][h*32+d]   (1024 x 128)
//   W3t[j*1024 + h*256+c] = sum_d Wv[c][h*32+d] * Wo[h*32+d][j]   (128 x 1024)
// ---------------------------------------------------------------------------
__global__ __launch_bounds__(256) void precompute_w(
    const float* __restrict__ Wq, const float* __restrict__ Wk,
    const float* __restrict__ Wv, const float* __restrict__ Wo,
    unsigned short* __restrict__ Mt, unsigned short* __restrict__ W3t) {
    int gid = blockIdx.x * 256 + threadIdx.x;
    if (gid < 131072) {
        int p = gid >> 7;          // h*256+c
        int i = gid & 127;
        int h = p >> 8;
        int c = p & 255;
        float s = 0.f;
        #pragma unroll
        for (int d = 0; d < 32; ++d)
            s += Wq[i * 128 + h * 32 + d] * Wk[c * 128 + h * 32 + d];
        Mt[gid] = f2bs(s);
    } else {
        int o = gid - 131072;
        int j = o >> 10;
        int rest = o & 1023;
        int h = rest >> 8;
        int c = rest & 255;
        float s = 0.f;
        #pragma unroll
        for (int d = 0; d < 32; ++d)
            s += Wv[c * 128 + h * 32 + d] * Wo[(h * 32 + d) * 128 + j];
        W3t[o] = f2bs(s);
    }
}

// h_V (fp32) -> bf16, 8 elems/thread
__global__ __launch_bounds__(256) void convert_hv(
    const float* __restrict__ hV, unsigned short* __restrict__ hVb) {
    int gid = blockIdx.x * 256 + threadIdx.x;     // 196608 threads
    const float4* src = (const float4*)hV;
    float4 a = src[gid * 2];
    float4 b = src[gid * 2 + 1];
    uint4 p;
    p.x = pack2(a.x, a.y);
    p.y = pack2(a.z, a.w);
    p.z = pack2(b.x, b.y);
    p.w = pack2(b.z, b.w);
    ((uint4*)hVb)[gid] = p;
}

// ---------------------------------------------------------------------------
// bf16 MFMA GEMM, B^T input:  C(MxN) = A(MxK) @ Bt(NxK)^T
// block = 256 thr (4 waves), BM=64 (16 rows/wave), BN=128, BK=32
// ---------------------------------------------------------------------------
template <bool OUT_BF16>
__global__ __launch_bounds__(256) void gemm_bt_bf16(
    const unsigned short* __restrict__ A, const unsigned short* __restrict__ Bt,
    void* __restrict__ C, int M, int N, int K) {
    constexpr int BM = 64, BN = 128, BK = 32, PAD = 8;
    constexpr int NT = BN / 16;                       // 8 n-tiles per wave
    __shared__ unsigned short As[BM][BK + PAD];       // 5 KB
    __shared__ unsigned short Bs[BN][BK + PAD];       // 10 KB
    const int tid  = threadIdx.x;
    const int wave = tid >> 6;
    const int lane = tid & 63;
    const int quad = lane >> 4;
    const int l16  = lane & 15;
    const int bm0 = blockIdx.x * BM;
    const int bn0 = blockIdx.y * BN;

    f32x4 acc[NT];
    #pragma unroll
    for (int j = 0; j < NT; ++j) acc[j] = (f32x4){0.f, 0.f, 0.f, 0.f};

    for (int kk = 0; kk < K; kk += BK) {
        {   // stage A: 64*32/8 = 256 chunks (1/thread)
            int row = tid >> 2, off = (tid & 3) * 8;
            *(uint4*)&As[row][off] =
                *(const uint4*)&A[(size_t)(bm0 + row) * K + kk + off];
        }
        #pragma unroll
        for (int i = 0; i < 2; ++i) {   // stage Bt: 128*32/8 = 512 chunks
            int c = tid * 2 + i;
            int row = c >> 2, off = (c & 3) * 8;
            *(uint4*)&Bs[row][off] =
                *(const uint4*)&Bt[(size_t)(bn0 + row) * K + kk + off];
        }
        __syncthreads();
        bf16x8 af = *(const bf16x8*)&As[wave * 16 + l16][quad * 8];
        #pragma unroll
        for (int j = 0; j < NT; ++j) {
            bf16x8 bf = *(const bf16x8*)&Bs[j * 16 + l16][quad * 8];
            acc[j] = __builtin_amdgcn_mfma_f32_16x16x32_bf16(af, bf, acc[j], 0, 0, 0);
        }
        __syncthreads();
    }
    // C/D layout: col = lane&15, row = quad*4 + reg  (m89-verified)
    int row0 = bm0 + wave * 16 + quad * 4;
    #pragma unroll
    for (int j = 0; j < NT; ++j) {
        int col = bn0 + j * 16 + l16;
        #pragma unroll
        for (int r = 0; r < 4; ++r) {
            if (OUT_BF16)
                ((unsigned short*)C)[(size_t)(row0 + r) * N + col] = f2bs(acc[j][r]);
            else
                ((float*)C)[(size_t)(row0 + r) * N + col] = acc[j][r];
        }
    }
}

// ---------------------------------------------------------------------------
// Fused masked neighbor attention. One block (4 waves) per site.
//  - active-row compaction from mask (skip ~50% of hEV reads)
//  - quarter-wave (16-lane) rows: 4 float4 loads/lane, in-flight 4-head dot,
//    4-stage shuffle reduce; EV staged to LDS as bf16
//  - softmax per head (wave h), evbar accum from LDS, bf16 output
// ---------------------------------------------------------------------------
__global__ __launch_bounds__(256) void attn_kernel(
    const float* __restrict__ hEV, const int* __restrict__ mask,
    const unsigned short* __restrict__ qt, unsigned short* __restrict__ evb) {
    __shared__ unsigned short evS[KNB * CIN];   // 15 KB (bf16)
    __shared__ float logitsL[4 * 32];
    __shared__ float attendL[4 * 32];
    __shared__ int   activeS[32];
    __shared__ int   naS;

    const int s = blockIdx.x;
    const int tid = threadIdx.x;
    const int lane = tid & 63;
    const int sub = tid & 15;

    // --- active-row list (wave 0) ---
    if (tid < 64) {
        int mk = (tid < KNB) ? mask[(size_t)s * KNB + tid] : 0;
        unsigned long long bal = __ballot(mk > 0);
        if (tid == 0) naS = __popcll(bal);
        if (mk > 0) activeS[__popcll(bal & ((1ull << tid) - 1))] = tid;
    }

    // --- q~ fragment: lane sub holds q~[h][sub*16 .. sub*16+15], 4 heads ---
    float qf[4][16];
    {
        const uint4* q4 = (const uint4*)(qt + (size_t)s * 1024);
        #pragma unroll
        for (int h = 0; h < 4; ++h) {
            #pragma unroll
            for (int c = 0; c < 2; ++c) {
                uint4 u = q4[h * 32 + sub * 2 + c];
                qf[h][c * 8 + 0] = bs2f(u.x & 0xffff);
                qf[h][c * 8 + 1] = bs2f(u.x >> 16);
                qf[h][c * 8 + 2] = bs2f(u.y & 0xffff);
                qf[h][c * 8 + 3] = bs2f(u.y >> 16);
                qf[h][c * 8 + 4] = bs2f(u.z & 0xffff);
                qf[h][c * 8 + 5] = bs2f(u.z >> 16);
                qf[h][c * 8 + 6] = bs2f(u.w & 0xffff);
                qf[h][c * 8 + 7] = bs2f(u.w >> 16);
            }
        }
    }
    __syncthreads();
    const int na = naS;

    // --- stream active rows: quarter-wave per row ---
    for (int r = tid >> 4; r < na; r += 16) {
        int k = activeS[r];
        const float4* row4 = (const float4*)(hEV + (size_t)s * (KNB * CIN) + (size_t)k * CIN);
        float vv[16];
        #pragma unroll
        for (int i = 0; i < 4; ++i)
            *(float4*)&vv[i * 4] = row4[sub * 4 + i];

        // stage to LDS as bf16 (32 B -> two b128 writes)
        uint4 p0, p1;
        p0.x = pack2(vv[0], vv[1]);  p0.y = pack2(vv[2], vv[3]);
        p0.z = pack2(vv[4], vv[5]);  p0.w = pack2(vv[6], vv[7]);
        p1.x = pack2(vv[8], vv[9]);  p1.y = pack2(vv[10], vv[11]);
        p1.z = pack2(vv[12], vv[13]); p1.w = pack2(vv[14], vv[15]);
        *(uint4*)&evS[r * CIN + sub * 16]     = p0;
        *(uint4*)&evS[r * CIN + sub * 16 + 8] = p1;

        float l[4] = {0.f, 0.f, 0.f, 0.f};
        #pragma unroll
        for (int h = 0; h < 4; ++h)
            #pragma unroll
            for (int c = 0; c < 16; ++c)
                l[h] = fmaf(vv[c], qf[h][c], l[h]);

        #pragma unroll
        for (int m = 1; m < 16; m <<= 1) {
            #pragma unroll
            for (int h = 0; h < 4; ++h) l[h] += __shfl_xor(l[h], m, 64);
        }
        if (sub == 0) {
            #pragma unroll
            for (int h = 0; h < 4; ++h) logitsL[h * 32 + r] = l[h] * RSQRT_D;
        }
    }
    __syncthreads();

    // --- softmax over active slots: wave h ---
    {
        int h = tid >> 6;
        float lg = (lane < na) ? logitsL[h * 32 + lane] : -FLT_MAX;
        float mx = lg;
        #pragma unroll
        for (int m = 1; m < 64; m <<= 1) mx = fmaxf(mx, __shfl_xor(mx, m, 64));
        float e = (lane < na) ? __expf(lg - mx) : 0.f;
        float sm = e;
        #pragma unroll
        for (int m = 1; m < 64; m <<= 1) sm += __shfl_xor(sm, m, 64);
        if (lane < na) attendL[h * 32 + lane] = e / sm;
    }
    __syncthreads();

    // --- evbar: thread t owns column c = t ---
    float a0 = 0.f, a1 = 0.f, a2 = 0.f, a3 = 0.f;
    for (int r = 0; r < na; ++r) {
        float evv = bs2f(evS[r * CIN + tid]);
        a0 = fmaf(attendL[r], evv, a0);
        a1 = fmaf(attendL[32 + r], evv, a1);
        a2 = fmaf(attendL[64 + r], evv, a2);
        a3 = fmaf(attendL[96 + r], evv, a3);
    }
    size_t ob = (size_t)s * 1024 + tid;
    evb[ob]       = f2bs(a0);
    evb[ob + 256] = f2bs(a1);
    evb[ob + 512] = f2bs(a2);
    evb[ob + 768] = f2bs(a3);
}

// ---------------------------------------------------------------------------
extern "C" void kernel_launch(void* const* d_in, const int* in_sizes, int n_in,
                              void* d_out, int out_size, void* d_ws, size_t ws_size,
                              hipStream_t stream) {
    const float* hV   = (const float*)d_in[0];
    const float* hEV  = (const float*)d_in[1];
    const int*   mask = (const int*)d_in[2];
    const float* Wq   = (const float*)d_in[3];
    const float* Wk   = (const float*)d_in[4];
    const float* Wv   = (const float*)d_in[5];
    const float* Wo   = (const float*)d_in[6];
    float* out = (float*)d_out;

    unsigned short* ws = (unsigned short*)d_ws;   // element = 2 B
    unsigned short* Mt   = ws;                            // 1024*128
    unsigned short* W3t  = ws + 131072;                   // 128*1024
    unsigned short* hVb  = ws + 262144;                   // 12288*128
    unsigned short* qt   = ws + 262144 + 1572864;         // 12288*1024
    unsigned short* evb  = qt + (size_t)SITES * 1024;     // 12288*1024
    size_t need = ((size_t)262144 + 1572864 + 2 * (size_t)SITES * 1024) * 2;
    if (ws_size < need) return;

    precompute_w<<<dim3(1024), dim3(256), 0, stream>>>(Wq, Wk, Wv, Wo, Mt, W3t);
    convert_hv<<<dim3(768), dim3(256), 0, stream>>>(hV, hVb);

    // qt (12288x1024, bf16) = hVb (12288x128) @ Mt^T
    gemm_bt_bf16<true><<<dim3(SITES / 64, 1024 / 128), dim3(256), 0, stream>>>(
        hVb, Mt, qt, SITES, 1024, 128);

    // fused masked attention -> evb (12288x1024, bf16)
    attn_kernel<<<dim3(SITES), dim3(256), 0, stream>>>(hEV, mask, qt, evb);

    // out (12288x128, fp32) = evb @ W3t^T
    gemm_bt_bf16<false><<<dim3(SITES / 64, 1), dim3(256), 0, stream>>>(
        evb, W3t, out, SITES, 128, 1024);
}